// Round 6
// baseline (362.702 us; speedup 1.0000x reference)
//
#include <hip/hip_runtime.h>

#define HID    128
#define SEQ    512
#define BATCH  256
#define DIM    300
#define VOCAB  50000
#define WT_FLOATS 40960  // 160 KB slot for packed-transposed W_ih (needs 38400)

// ---------------------------------------------------------------------------
// Kernel 0 (R4-proven): pack-transpose W_ih [128][300] -> Wt[k4][h][4].
// ---------------------------------------------------------------------------
__global__ __launch_bounds__(256)
void wtrans_kernel(const float* __restrict__ Wih, float* __restrict__ Wt)
{
    int idx = blockIdx.x * 256 + threadIdx.x;
    if (idx < HID * DIM) {
        int h = idx / DIM;
        int k = idx - h * DIM;
        Wt[(k >> 2) * (HID * 4) + h * 4 + (k & 3)] = Wih[idx];
    }
}

// ---------------------------------------------------------------------------
// Kernel A (R4-proven, ~96 µs): P[v][h] = emb[v,:]·W_ih[h,:] + b_ih + b_hh
// ---------------------------------------------------------------------------
#define ETP 20
#define VT  16
__global__ __launch_bounds__(128)
void proj_fast(const float* __restrict__ emb,
               const float* __restrict__ Wt,
               const float* __restrict__ bih,
               const float* __restrict__ bhh,
               float* __restrict__ P)
{
    __shared__ float et[DIM][ETP];   // transposed emb tile: et[k][r]
    const int t  = threadIdx.x;
    const int hp = t & 63;
    const int rg8 = (t >> 6) * 8;
    const int v0 = blockIdx.x * VT;

    #pragma unroll
    for (int r = 0; r < VT; ++r) {
        const float* src = emb + (size_t)(v0 + r) * DIM;
        for (int k = t; k < DIM; k += 128)
            et[k][r] = src[k];
    }
    __syncthreads();

    float a00=0.f,a10=0.f,a20=0.f,a30=0.f,a40=0.f,a50=0.f,a60=0.f,a70=0.f;
    float a01=0.f,a11=0.f,a21=0.f,a31=0.f,a41=0.f,a51=0.f,a61=0.f,a71=0.f;

    const float* wp0 = Wt + hp * 4;          // packed: [k4][h][4]
    const float* wp1 = Wt + (hp + 64) * 4;

    for (int k4 = 0; k4 < DIM / 4; ++k4) {
        const float4 wa4 = *(const float4*)(wp0 + k4 * (HID * 4));
        const float4 wb4 = *(const float4*)(wp1 + k4 * (HID * 4));
        #pragma unroll
        for (int jj = 0; jj < 4; ++jj) {
            const float wa = (jj==0)?wa4.x:(jj==1)?wa4.y:(jj==2)?wa4.z:wa4.w;
            const float wb = (jj==0)?wb4.x:(jj==1)?wb4.y:(jj==2)?wb4.z:wb4.w;
            const int k = k4 * 4 + jj;
            const float4 e0 = *(const float4*)(&et[k][rg8]);      // broadcast
            const float4 e1 = *(const float4*)(&et[k][rg8 + 4]);  // broadcast
            a00 = fmaf(wa, e0.x, a00);  a01 = fmaf(wb, e0.x, a01);
            a10 = fmaf(wa, e0.y, a10);  a11 = fmaf(wb, e0.y, a11);
            a20 = fmaf(wa, e0.z, a20);  a21 = fmaf(wb, e0.z, a21);
            a30 = fmaf(wa, e0.w, a30);  a31 = fmaf(wb, e0.w, a31);
            a40 = fmaf(wa, e1.x, a40);  a41 = fmaf(wb, e1.x, a41);
            a50 = fmaf(wa, e1.y, a50);  a51 = fmaf(wb, e1.y, a51);
            a60 = fmaf(wa, e1.z, a60);  a61 = fmaf(wb, e1.z, a61);
            a70 = fmaf(wa, e1.w, a70);  a71 = fmaf(wb, e1.w, a71);
        }
    }

    const float bb0 = bih[hp] + bhh[hp];
    const float bb1 = bih[hp + 64] + bhh[hp + 64];
    float* dst = P + (size_t)(v0 + rg8) * HID;
    dst[0*HID + hp] = a00 + bb0;  dst[0*HID + hp + 64] = a01 + bb1;
    dst[1*HID + hp] = a10 + bb0;  dst[1*HID + hp + 64] = a11 + bb1;
    dst[2*HID + hp] = a20 + bb0;  dst[2*HID + hp + 64] = a21 + bb1;
    dst[3*HID + hp] = a30 + bb0;  dst[3*HID + hp + 64] = a31 + bb1;
    dst[4*HID + hp] = a40 + bb0;  dst[4*HID + hp + 64] = a41 + bb1;
    dst[5*HID + hp] = a50 + bb0;  dst[5*HID + hp + 64] = a51 + bb1;
    dst[6*HID + hp] = a60 + bb0;  dst[6*HID + hp + 64] = a61 + bb1;
    dst[7*HID + hp] = a70 + bb0;  dst[7*HID + hp + 64] = a71 + bb1;
}

// ---------------------------------------------------------------------------
// Kernel A (fallback, R3-proven): used only if ws_size can't fit Wt + P.
// ---------------------------------------------------------------------------
__global__ __launch_bounds__(128)
void proj_fallback(const float* __restrict__ emb,
                   const float* __restrict__ Wih,
                   const float* __restrict__ bih,
                   const float* __restrict__ bhh,
                   float* __restrict__ P)
{
    __shared__ float et[DIM][ETP];
    const int t  = threadIdx.x;
    const int hp = t & 63;
    const int rg8 = (t >> 6) * 8;
    const int v0 = blockIdx.x * VT;

    #pragma unroll
    for (int r = 0; r < VT; ++r) {
        const float* src = emb + (size_t)(v0 + r) * DIM;
        for (int k = t; k < DIM; k += 128)
            et[k][r] = src[k];
    }
    __syncthreads();

    float a00=0.f,a10=0.f,a20=0.f,a30=0.f,a40=0.f,a50=0.f,a60=0.f,a70=0.f;
    float a01=0.f,a11=0.f,a21=0.f,a31=0.f,a41=0.f,a51=0.f,a61=0.f,a71=0.f;

    const float* w0 = Wih + (size_t)hp * DIM;
    const float* w1 = Wih + (size_t)(hp + 64) * DIM;

    for (int k4 = 0; k4 < DIM / 4; ++k4) {
        const float4 wa4 = *(const float4*)(w0 + k4 * 4);
        const float4 wb4 = *(const float4*)(w1 + k4 * 4);
        #pragma unroll
        for (int jj = 0; jj < 4; ++jj) {
            const float wa = (jj==0)?wa4.x:(jj==1)?wa4.y:(jj==2)?wa4.z:wa4.w;
            const float wb = (jj==0)?wb4.x:(jj==1)?wb4.y:(jj==2)?wb4.z:wb4.w;
            const int k = k4 * 4 + jj;
            const float4 e0 = *(const float4*)(&et[k][rg8]);
            const float4 e1 = *(const float4*)(&et[k][rg8 + 4]);
            a00 = fmaf(wa, e0.x, a00);  a01 = fmaf(wb, e0.x, a01);
            a10 = fmaf(wa, e0.y, a10);  a11 = fmaf(wb, e0.y, a11);
            a20 = fmaf(wa, e0.z, a20);  a21 = fmaf(wb, e0.z, a21);
            a30 = fmaf(wa, e0.w, a30);  a31 = fmaf(wb, e0.w, a31);
            a40 = fmaf(wa, e1.x, a40);  a41 = fmaf(wb, e1.x, a41);
            a50 = fmaf(wa, e1.y, a50);  a51 = fmaf(wb, e1.y, a51);
            a60 = fmaf(wa, e1.z, a60);  a61 = fmaf(wb, e1.z, a61);
            a70 = fmaf(wa, e1.w, a70);  a71 = fmaf(wb, e1.w, a71);
        }
    }

    const float bb0 = bih[hp] + bhh[hp];
    const float bb1 = bih[hp + 64] + bhh[hp + 64];
    float* dst = P + (size_t)(v0 + rg8) * HID;
    dst[0*HID + hp] = a00 + bb0;  dst[0*HID + hp + 64] = a01 + bb1;
    dst[1*HID + hp] = a10 + bb0;  dst[1*HID + hp + 64] = a11 + bb1;
    dst[2*HID + hp] = a20 + bb0;  dst[2*HID + hp + 64] = a21 + bb1;
    dst[3*HID + hp] = a30 + bb0;  dst[3*HID + hp + 64] = a31 + bb1;
    dst[4*HID + hp] = a40 + bb0;  dst[4*HID + hp + 64] = a41 + bb1;
    dst[5*HID + hp] = a50 + bb0;  dst[5*HID + hp + 64] = a51 + bb1;
    dst[6*HID + hp] = a60 + bb0;  dst[6*HID + hp + 64] = a61 + bb1;
    dst[7*HID + hp] = a70 + bb0;  dst[7*HID + hp + 64] = a71 + bb1;
}

// ---------------------------------------------------------------------------
// Kernel B: RNN, block=256 (4 waves, 1/SIMD), k-split 2.
// Lane t: row i=t>>1, k-half kh=t&1 (64 W_hh values = 16 float4 in VGPRs).
// Issue model (R3/R5-fitted: step = 2*wavesPerSIMD*N + S): N≈100, wps=1
// -> 200 cyc issue vs R3's 440. Reduce = ONE DPP pair-swap + add. h-write
// unconditional from both pair lanes (identical value+addr, deterministic).
// P prefetched 8 steps ahead in named regs (vm-drain amortized /8).
// ---------------------------------------------------------------------------
__global__ __launch_bounds__(256)
void rnn_kernel(const int* __restrict__ x,
                const float* __restrict__ Whh,
                const float* __restrict__ P,
                const float* __restrict__ fcw,
                const float* __restrict__ fcb,
                float* __restrict__ out)
{
    __shared__ float h0b[HID];
    __shared__ float h1b[HID];
    __shared__ int   toff[SEQ];     // token*HID, premultiplied
    __shared__ float red[HID];

    const int t  = threadIdx.x;     // 0..255
    const int b  = blockIdx.x;
    const int i  = t >> 1;          // output row 0..127
    const int kh = t & 1;           // k-half
    const int kbase = kh * 64;      // float offset into h

    toff[t]       = x[b * SEQ + t] * HID;
    toff[t + 256] = x[b * SEQ + t + 256] * HID;
    if (t < HID) h0b[t] = 0.f;

    // W_hh[i][kbase .. kbase+63] in 16 float4 registers
    float4 w[16];
    #pragma unroll
    for (int j = 0; j < 16; ++j)
        w[j] = *(const float4*)(Whh + (size_t)i * HID + kbase + j * 4);
    __syncthreads();

    float x0 = P[toff[0] + i], x1 = P[toff[1] + i];
    float x2 = P[toff[2] + i], x3 = P[toff[3] + i];
    float x4 = P[toff[4] + i], x5 = P[toff[5] + i];
    float x6 = P[toff[6] + i], x7 = P[toff[7] + i];
    float hmax = -3.0e38f, hsum = 0.f;

#define STEP(HRD, HWR, XT) do {                                               \
        float ac0 = 0.f, ac1 = 0.f, ac2 = 0.f, ac3 = 0.f;                     \
        _Pragma("unroll")                                                     \
        for (int j = 0; j < 16; ++j) {                                        \
            const float4 hv = *(const float4*)((HRD) + kbase + j * 4);        \
            float* ap = (j & 3) == 0 ? &ac0 : (j & 3) == 1 ? &ac1             \
                       : (j & 3) == 2 ? &ac2 : &ac3;                          \
            *ap = fmaf(w[j].x, hv.x, *ap);                                    \
            *ap = fmaf(w[j].y, hv.y, *ap);                                    \
            *ap = fmaf(w[j].z, hv.z, *ap);                                    \
            *ap = fmaf(w[j].w, hv.w, *ap);                                    \
        }                                                                     \
        float acc = (ac0 + ac1) + (ac2 + ac3);                                \
        { int xx_ = __builtin_amdgcn_update_dpp(0, __float_as_int(acc),       \
                                                0xB1, 0xF, 0xF, true);        \
          acc += __int_as_float(xx_); }   /* pair sum: both lanes full */     \
        const float z = (XT) + acc;                                           \
        const float e = __builtin_amdgcn_exp2f(z * 2.8853900817779268f);      \
        const float hnew = fmaf(-2.f, __builtin_amdgcn_rcpf(e + 1.f), 1.f);   \
        hmax = fmaxf(hmax, hnew);                                             \
        hsum += hnew;                                                         \
        (HWR)[i] = hnew;   /* both pair lanes: same value, same address */    \
        __syncthreads();                                                      \
    } while (0)

    for (int s = 0; s < SEQ - 8; s += 8) {
        const float n0 = P[toff[s +  8] + i];
        const float n1 = P[toff[s +  9] + i];
        const float n2 = P[toff[s + 10] + i];
        const float n3 = P[toff[s + 11] + i];
        const float n4 = P[toff[s + 12] + i];
        const float n5 = P[toff[s + 13] + i];
        const float n6 = P[toff[s + 14] + i];
        const float n7 = P[toff[s + 15] + i];
        STEP(h0b, h1b, x0);
        STEP(h1b, h0b, x1);
        STEP(h0b, h1b, x2);
        STEP(h1b, h0b, x3);
        STEP(h0b, h1b, x4);
        STEP(h1b, h0b, x5);
        STEP(h0b, h1b, x6);
        STEP(h1b, h0b, x7);
        x0 = n0; x1 = n1; x2 = n2; x3 = n3;
        x4 = n4; x5 = n5; x6 = n6; x7 = n7;
    }
    STEP(h0b, h1b, x0);
    STEP(h1b, h0b, x1);
    STEP(h0b, h1b, x2);
    STEP(h1b, h0b, x3);
    STEP(h0b, h1b, x4);
    STEP(h1b, h0b, x5);
    STEP(h0b, h1b, x6);
    STEP(h1b, h0b, x7);
#undef STEP

    // fused pooling + FC: out[b] = fcw[0:128]·hmax + fcw[128:256]·mean + fcb
    if (kh == 0)
        red[i] = fcw[i] * hmax + fcw[HID + i] * (hsum * (1.f / 512.f));
    __syncthreads();
    if (t < 64) {
        float v = red[t] + red[t + 64];
        #pragma unroll
        for (int m = 32; m >= 1; m >>= 1) v += __shfl_xor(v, m);
        if (t == 0) out[b] = v + fcb[0];
    }
}

// ---------------------------------------------------------------------------
extern "C" void kernel_launch(void* const* d_in, const int* in_sizes, int n_in,
                              void* d_out, int out_size, void* d_ws, size_t ws_size,
                              hipStream_t stream)
{
    const int*   x   = (const int*)  d_in[0];
    const float* emb = (const float*)d_in[1];
    const float* Wih = (const float*)d_in[2];
    const float* Whh = (const float*)d_in[3];
    const float* bih = (const float*)d_in[4];
    const float* bhh = (const float*)d_in[5];
    const float* fcw = (const float*)d_in[6];
    const float* fcb = (const float*)d_in[7];

    float* base = (float*)d_ws;
    const size_t need = (WT_FLOATS + (size_t)VOCAB * HID) * sizeof(float);
    float* P;

    if (ws_size >= need) {
        float* Wt = base;                 // 160 KB, inside d_ws (proven R4)
        P = base + WT_FLOATS;
        wtrans_kernel<<<(HID * DIM + 255) / 256, 256, 0, stream>>>(Wih, Wt);
        proj_fast<<<VOCAB / VT, 128, 0, stream>>>(emb, Wt, bih, bhh, P);
    } else {
        P = base;
        proj_fallback<<<VOCAB / VT, 128, 0, stream>>>(emb, Wih, bih, bhh, P);
    }

    rnn_kernel<<<BATCH, 256, 0, stream>>>(x, Whh, P, fcw, fcb, (float*)d_out);
}

// Round 7
// 280.737 us; speedup vs baseline: 1.2920x; 1.2920x over previous
//
#include <hip/hip_runtime.h>

#define HID    128
#define SEQ    512
#define BATCH  256
#define DIM    300
#define VOCAB  50000
#define WT_FLOATS 40960  // 160 KB slot for packed-transposed W_ih (needs 38400)

// ---------------------------------------------------------------------------
// Kernel 0 (R4-proven): pack-transpose W_ih [128][300] -> Wt[k4][h][4].
// ---------------------------------------------------------------------------
__global__ __launch_bounds__(256)
void wtrans_kernel(const float* __restrict__ Wih, float* __restrict__ Wt)
{
    int idx = blockIdx.x * 256 + threadIdx.x;
    if (idx < HID * DIM) {
        int h = idx / DIM;
        int k = idx - h * DIM;
        Wt[(k >> 2) * (HID * 4) + h * 4 + (k & 3)] = Wih[idx];
    }
}

// ---------------------------------------------------------------------------
// Kernel A (R4-proven, ~96 µs): P[v][h] = emb[v,:]·W_ih[h,:] + b_ih + b_hh
// ---------------------------------------------------------------------------
#define ETP 20
#define VT  16
__global__ __launch_bounds__(128)
void proj_fast(const float* __restrict__ emb,
               const float* __restrict__ Wt,
               const float* __restrict__ bih,
               const float* __restrict__ bhh,
               float* __restrict__ P)
{
    __shared__ float et[DIM][ETP];   // transposed emb tile: et[k][r]
    const int t  = threadIdx.x;
    const int hp = t & 63;
    const int rg8 = (t >> 6) * 8;
    const int v0 = blockIdx.x * VT;

    #pragma unroll
    for (int r = 0; r < VT; ++r) {
        const float* src = emb + (size_t)(v0 + r) * DIM;
        for (int k = t; k < DIM; k += 128)
            et[k][r] = src[k];
    }
    __syncthreads();

    float a00=0.f,a10=0.f,a20=0.f,a30=0.f,a40=0.f,a50=0.f,a60=0.f,a70=0.f;
    float a01=0.f,a11=0.f,a21=0.f,a31=0.f,a41=0.f,a51=0.f,a61=0.f,a71=0.f;

    const float* wp0 = Wt + hp * 4;          // packed: [k4][h][4]
    const float* wp1 = Wt + (hp + 64) * 4;

    for (int k4 = 0; k4 < DIM / 4; ++k4) {
        const float4 wa4 = *(const float4*)(wp0 + k4 * (HID * 4));
        const float4 wb4 = *(const float4*)(wp1 + k4 * (HID * 4));
        #pragma unroll
        for (int jj = 0; jj < 4; ++jj) {
            const float wa = (jj==0)?wa4.x:(jj==1)?wa4.y:(jj==2)?wa4.z:wa4.w;
            const float wb = (jj==0)?wb4.x:(jj==1)?wb4.y:(jj==2)?wb4.z:wb4.w;
            const int k = k4 * 4 + jj;
            const float4 e0 = *(const float4*)(&et[k][rg8]);      // broadcast
            const float4 e1 = *(const float4*)(&et[k][rg8 + 4]);  // broadcast
            a00 = fmaf(wa, e0.x, a00);  a01 = fmaf(wb, e0.x, a01);
            a10 = fmaf(wa, e0.y, a10);  a11 = fmaf(wb, e0.y, a11);
            a20 = fmaf(wa, e0.z, a20);  a21 = fmaf(wb, e0.z, a21);
            a30 = fmaf(wa, e0.w, a30);  a31 = fmaf(wb, e0.w, a31);
            a40 = fmaf(wa, e1.x, a40);  a41 = fmaf(wb, e1.x, a41);
            a50 = fmaf(wa, e1.y, a50);  a51 = fmaf(wb, e1.y, a51);
            a60 = fmaf(wa, e1.z, a60);  a61 = fmaf(wb, e1.z, a61);
            a70 = fmaf(wa, e1.w, a70);  a71 = fmaf(wb, e1.w, a71);
        }
    }

    const float bb0 = bih[hp] + bhh[hp];
    const float bb1 = bih[hp + 64] + bhh[hp + 64];
    float* dst = P + (size_t)(v0 + rg8) * HID;
    dst[0*HID + hp] = a00 + bb0;  dst[0*HID + hp + 64] = a01 + bb1;
    dst[1*HID + hp] = a10 + bb0;  dst[1*HID + hp + 64] = a11 + bb1;
    dst[2*HID + hp] = a20 + bb0;  dst[2*HID + hp + 64] = a21 + bb1;
    dst[3*HID + hp] = a30 + bb0;  dst[3*HID + hp + 64] = a31 + bb1;
    dst[4*HID + hp] = a40 + bb0;  dst[4*HID + hp + 64] = a41 + bb1;
    dst[5*HID + hp] = a50 + bb0;  dst[5*HID + hp + 64] = a51 + bb1;
    dst[6*HID + hp] = a60 + bb0;  dst[6*HID + hp + 64] = a61 + bb1;
    dst[7*HID + hp] = a70 + bb0;  dst[7*HID + hp + 64] = a71 + bb1;
}

// ---------------------------------------------------------------------------
// Kernel A (fallback, R3-proven): used only if ws_size can't fit Wt + P.
// ---------------------------------------------------------------------------
__global__ __launch_bounds__(128)
void proj_fallback(const float* __restrict__ emb,
                   const float* __restrict__ Wih,
                   const float* __restrict__ bih,
                   const float* __restrict__ bhh,
                   float* __restrict__ P)
{
    __shared__ float et[DIM][ETP];
    const int t  = threadIdx.x;
    const int hp = t & 63;
    const int rg8 = (t >> 6) * 8;
    const int v0 = blockIdx.x * VT;

    #pragma unroll
    for (int r = 0; r < VT; ++r) {
        const float* src = emb + (size_t)(v0 + r) * DIM;
        for (int k = t; k < DIM; k += 128)
            et[k][r] = src[k];
    }
    __syncthreads();

    float a00=0.f,a10=0.f,a20=0.f,a30=0.f,a40=0.f,a50=0.f,a60=0.f,a70=0.f;
    float a01=0.f,a11=0.f,a21=0.f,a31=0.f,a41=0.f,a51=0.f,a61=0.f,a71=0.f;

    const float* w0 = Wih + (size_t)hp * DIM;
    const float* w1 = Wih + (size_t)(hp + 64) * DIM;

    for (int k4 = 0; k4 < DIM / 4; ++k4) {
        const float4 wa4 = *(const float4*)(w0 + k4 * 4);
        const float4 wb4 = *(const float4*)(w1 + k4 * 4);
        #pragma unroll
        for (int jj = 0; jj < 4; ++jj) {
            const float wa = (jj==0)?wa4.x:(jj==1)?wa4.y:(jj==2)?wa4.z:wa4.w;
            const float wb = (jj==0)?wb4.x:(jj==1)?wb4.y:(jj==2)?wb4.z:wb4.w;
            const int k = k4 * 4 + jj;
            const float4 e0 = *(const float4*)(&et[k][rg8]);
            const float4 e1 = *(const float4*)(&et[k][rg8 + 4]);
            a00 = fmaf(wa, e0.x, a00);  a01 = fmaf(wb, e0.x, a01);
            a10 = fmaf(wa, e0.y, a10);  a11 = fmaf(wb, e0.y, a11);
            a20 = fmaf(wa, e0.z, a20);  a21 = fmaf(wb, e0.z, a21);
            a30 = fmaf(wa, e0.w, a30);  a31 = fmaf(wb, e0.w, a31);
            a40 = fmaf(wa, e1.x, a40);  a41 = fmaf(wb, e1.x, a41);
            a50 = fmaf(wa, e1.y, a50);  a51 = fmaf(wb, e1.y, a51);
            a60 = fmaf(wa, e1.z, a60);  a61 = fmaf(wb, e1.z, a61);
            a70 = fmaf(wa, e1.w, a70);  a71 = fmaf(wb, e1.w, a71);
        }
    }

    const float bb0 = bih[hp] + bhh[hp];
    const float bb1 = bih[hp + 64] + bhh[hp + 64];
    float* dst = P + (size_t)(v0 + rg8) * HID;
    dst[0*HID + hp] = a00 + bb0;  dst[0*HID + hp + 64] = a01 + bb1;
    dst[1*HID + hp] = a10 + bb0;  dst[1*HID + hp + 64] = a11 + bb1;
    dst[2*HID + hp] = a20 + bb0;  dst[2*HID + hp + 64] = a21 + bb1;
    dst[3*HID + hp] = a30 + bb0;  dst[3*HID + hp + 64] = a31 + bb1;
    dst[4*HID + hp] = a40 + bb0;  dst[4*HID + hp + 64] = a41 + bb1;
    dst[5*HID + hp] = a50 + bb0;  dst[5*HID + hp + 64] = a51 + bb1;
    dst[6*HID + hp] = a60 + bb0;  dst[6*HID + hp + 64] = a61 + bb1;
    dst[7*HID + hp] = a70 + bb0;  dst[7*HID + hp + 64] = a71 + bb1;
}

// ---------------------------------------------------------------------------
// Kernel B: RNN, 512 thr (R3 structure: i=t>>2, kq=t&3, DPP quad reduce,
// rotated conflict-free h reads). NEW: x-projections pre-gathered per
// 64-step chunk into double-buffered LDS xb[2][64][128] (staged once per
// chunk: 4 dwordx4 + 4 ds_write_b128 per thread). Steady-state steps have
// ZERO outstanding vmem -> __syncthreads' vmcnt(0) drain costs nothing;
// per-step xt is one conflict-free ds_read_b32.
// ---------------------------------------------------------------------------
__device__ __forceinline__ float quad_sum(float v)
{
    // xor1: quad_perm [1,0,3,2]=0xB1 ; xor2: quad_perm [2,3,0,1]=0x4E
    int x1 = __builtin_amdgcn_update_dpp(0, __float_as_int(v), 0xB1, 0xF, 0xF, true);
    v += __int_as_float(x1);
    int x2 = __builtin_amdgcn_update_dpp(0, __float_as_int(v), 0x4E, 0xF, 0xF, true);
    v += __int_as_float(x2);
    return v;   // all 4 lanes of the quad hold the sum
}

__global__ __launch_bounds__(512)
void rnn_kernel(const int* __restrict__ x,
                const float* __restrict__ Whh,
                const float* __restrict__ P,
                const float* __restrict__ fcw,
                const float* __restrict__ fcb,
                float* __restrict__ out)
{
    __shared__ float h0b[HID];
    __shared__ float h1b[HID];
    __shared__ int   toff[SEQ];          // token*HID, premultiplied
    __shared__ float xb[2 * 64 * HID];   // 64 KB: double-buffered x-proj chunks
    __shared__ float red[HID];

    const int t  = threadIdx.x;
    const int b  = blockIdx.x;
    const int i  = t >> 2;
    const int kq = t & 3;

    toff[t] = x[b * SEQ + t] * HID;
    if (t < HID) h0b[t] = 0.f;

    // W_hh[i][kq*32 + rot(j)*4 .. +3]; rotation -> 4 distinct bank-quads
    // per inst (R3-measured 0 conflicts).
    float4 w[8];
    #pragma unroll
    for (int j = 0; j < 8; ++j) {
        const int pj = (j + 2 * kq) & 7;
        w[j] = *(const float4*)(Whh + (size_t)i * HID + kq * 32 + pj * 4);
    }
    __syncthreads();   // toff visible

// Stage chunk `cn` (64 steps x 128 floats = 32 KB) into xb half (cn&1).
// Wave-inst q covers a contiguous 1 KB of the chunk: lane-linear ds_write
// (conflict-free); global side reads two full 512B P-rows per inst.
#define STAGE(cn) do {                                                        \
        const int w_ = t >> 6, l_ = t & 63;                                   \
        const int base_ = ((cn) & 1) * (64 * HID);                            \
        _Pragma("unroll")                                                     \
        for (int q_ = 0; q_ < 4; ++q_) {                                      \
            const int row_ = w_ * 8 + q_ * 2 + (l_ >> 5);                     \
            const int col_ = (l_ & 31) * 4;                                   \
            const int off_ = toff[(cn) * 64 + row_] + col_;                   \
            const float4 v_ = *(const float4*)(P + off_);                     \
            *(float4*)(&xb[base_ + row_ * HID + col_]) = v_;                  \
        }                                                                     \
    } while (0)

    STAGE(0);
    __syncthreads();   // chunk 0 visible (drains its vmcnt once)

    float hmax = -3.0e38f, hsum = 0.f;

#define STEP(HRD, HWR, XPTR, SOFF) do {                                       \
        const float xt = (XPTR)[(SOFF) * HID];                                \
        float ac0 = 0.f, ac1 = 0.f, ac2 = 0.f, ac3 = 0.f;                     \
        _Pragma("unroll")                                                     \
        for (int j = 0; j < 8; ++j) {                                         \
            const int pj = (j + 2 * kq) & 7;                                  \
            const float4 h4 = *(const float4*)((HRD) + kq * 32 + pj * 4);     \
            float* ap = (j & 3) == 0 ? &ac0 : (j & 3) == 1 ? &ac1             \
                       : (j & 3) == 2 ? &ac2 : &ac3;                          \
            *ap = fmaf(w[j].x, h4.x, *ap);                                    \
            *ap = fmaf(w[j].y, h4.y, *ap);                                    \
            *ap = fmaf(w[j].z, h4.z, *ap);                                    \
            *ap = fmaf(w[j].w, h4.w, *ap);                                    \
        }                                                                     \
        float acc = (ac0 + ac1) + (ac2 + ac3);                                \
        acc = quad_sum(acc);                                                  \
        const float z = xt + acc;                                             \
        const float e = __builtin_amdgcn_exp2f(z * 2.8853900817779268f);      \
        const float hnew = fmaf(-2.f, __builtin_amdgcn_rcpf(e + 1.f), 1.f);   \
        hmax = fmaxf(hmax, hnew);                                             \
        hsum += hnew;                                                         \
        if (kq == 0) (HWR)[i] = hnew;                                         \
        __syncthreads();                                                      \
    } while (0)

    for (int c = 0; c < 8; ++c) {
        if (c < 7) STAGE(c + 1);                 // double-buffered prefetch;
                                                 // vmcnt drain amortized /64
        const float* xp = &xb[(c & 1) * (64 * HID) + i];
        #pragma unroll 4
        for (int u = 0; u < 32; ++u) {
            STEP(h0b, h1b, xp, u * 2);
            STEP(h1b, h0b, xp, u * 2 + 1);
        }
    }
#undef STEP
#undef STAGE

    // fused pooling + FC: out[b] = fcw[0:128]·hmax + fcw[128:256]·mean + fcb
    if (kq == 0)
        red[i] = fcw[i] * hmax + fcw[HID + i] * (hsum * (1.f / 512.f));
    __syncthreads();
    if (t < 64) {
        float v = red[t] + red[t + 64];
        #pragma unroll
        for (int m = 32; m >= 1; m >>= 1) v += __shfl_xor(v, m);
        if (t == 0) out[b] = v + fcb[0];
    }
}

// ---------------------------------------------------------------------------
extern "C" void kernel_launch(void* const* d_in, const int* in_sizes, int n_in,
                              void* d_out, int out_size, void* d_ws, size_t ws_size,
                              hipStream_t stream)
{
    const int*   x   = (const int*)  d_in[0];
    const float* emb = (const float*)d_in[1];
    const float* Wih = (const float*)d_in[2];
    const float* Whh = (const float*)d_in[3];
    const float* bih = (const float*)d_in[4];
    const float* bhh = (const float*)d_in[5];
    const float* fcw = (const float*)d_in[6];
    const float* fcb = (const float*)d_in[7];

    float* base = (float*)d_ws;
    const size_t need = (WT_FLOATS + (size_t)VOCAB * HID) * sizeof(float);
    float* P;

    if (ws_size >= need) {
        float* Wt = base;                 // 160 KB, inside d_ws (proven R4)
        P = base + WT_FLOATS;
        wtrans_kernel<<<(HID * DIM + 255) / 256, 256, 0, stream>>>(Wih, Wt);
        proj_fast<<<VOCAB / VT, 128, 0, stream>>>(emb, Wt, bih, bhh, P);
    } else {
        P = base;
        proj_fallback<<<VOCAB / VT, 128, 0, stream>>>(emb, Wih, bih, bhh, P);
    }

    rnn_kernel<<<BATCH, 512, 0, stream>>>(x, Whh, P, fcw, fcb, (float*)d_out);
}

// Round 8
// 233.802 us; speedup vs baseline: 1.5513x; 1.2007x over previous
//
#include <hip/hip_runtime.h>

#define HID    128
#define SEQ    512
#define BATCH  256
#define DIM    300
#define VOCAB  50000
#define WT_FLOATS 40960  // 160 KB slot for packed-transposed W_ih (needs 38400)

// ---------------------------------------------------------------------------
// Kernel 0 (R4-proven): pack-transpose W_ih [128][300] -> Wt[k4][h][4].
// ---------------------------------------------------------------------------
__global__ __launch_bounds__(256)
void wtrans_kernel(const float* __restrict__ Wih, float* __restrict__ Wt)
{
    int idx = blockIdx.x * 256 + threadIdx.x;
    if (idx < HID * DIM) {
        int h = idx / DIM;
        int k = idx - h * DIM;
        Wt[(k >> 2) * (HID * 4) + h * 4 + (k & 3)] = Wih[idx];
    }
}

// ---------------------------------------------------------------------------
// Kernel A: proj with COALESCED staging. Lane (rr=t>>3, kk=t&7) reads row
// v0+rr as float4 (8-lane 128B segments, ~10/lane) and scatters into the
// transposed et[k][r] via 4x ds_write_b32 (<=4-way bank, negligible).
// Inner loop byte-identical to R4-proven proj_fast.
// ---------------------------------------------------------------------------
#define ETP 20
#define VT  16
__global__ __launch_bounds__(128)
void proj_fast(const float* __restrict__ emb,
               const float* __restrict__ Wt,
               const float* __restrict__ bih,
               const float* __restrict__ bhh,
               float* __restrict__ P)
{
    __shared__ float et[DIM][ETP];   // transposed emb tile: et[k][r]
    const int t  = threadIdx.x;
    const int hp = t & 63;
    const int rg8 = (t >> 6) * 8;
    const int v0 = blockIdx.x * VT;

    // coalesced staging: rr = local row, kk = float4 phase
    {
        const int rr = t >> 3;          // 0..15
        const int kk = t & 7;           // 0..7
        const float* src = emb + (size_t)(v0 + rr) * DIM;
        #pragma unroll
        for (int p = 0; p < 10; ++p) {
            const int f4 = kk + 8 * p;  // 0..74
            if (f4 < DIM / 4) {
                const float4 ev = *(const float4*)(src + f4 * 4);
                et[4 * f4 + 0][rr] = ev.x;
                et[4 * f4 + 1][rr] = ev.y;
                et[4 * f4 + 2][rr] = ev.z;
                et[4 * f4 + 3][rr] = ev.w;
            }
        }
    }
    __syncthreads();

    float a00=0.f,a10=0.f,a20=0.f,a30=0.f,a40=0.f,a50=0.f,a60=0.f,a70=0.f;
    float a01=0.f,a11=0.f,a21=0.f,a31=0.f,a41=0.f,a51=0.f,a61=0.f,a71=0.f;

    const float* wp0 = Wt + hp * 4;          // packed: [k4][h][4]
    const float* wp1 = Wt + (hp + 64) * 4;

    for (int k4 = 0; k4 < DIM / 4; ++k4) {
        const float4 wa4 = *(const float4*)(wp0 + k4 * (HID * 4));
        const float4 wb4 = *(const float4*)(wp1 + k4 * (HID * 4));
        #pragma unroll
        for (int jj = 0; jj < 4; ++jj) {
            const float wa = (jj==0)?wa4.x:(jj==1)?wa4.y:(jj==2)?wa4.z:wa4.w;
            const float wb = (jj==0)?wb4.x:(jj==1)?wb4.y:(jj==2)?wb4.z:wb4.w;
            const int k = k4 * 4 + jj;
            const float4 e0 = *(const float4*)(&et[k][rg8]);      // broadcast
            const float4 e1 = *(const float4*)(&et[k][rg8 + 4]);  // broadcast
            a00 = fmaf(wa, e0.x, a00);  a01 = fmaf(wb, e0.x, a01);
            a10 = fmaf(wa, e0.y, a10);  a11 = fmaf(wb, e0.y, a11);
            a20 = fmaf(wa, e0.z, a20);  a21 = fmaf(wb, e0.z, a21);
            a30 = fmaf(wa, e0.w, a30);  a31 = fmaf(wb, e0.w, a31);
            a40 = fmaf(wa, e1.x, a40);  a41 = fmaf(wb, e1.x, a41);
            a50 = fmaf(wa, e1.y, a50);  a51 = fmaf(wb, e1.y, a51);
            a60 = fmaf(wa, e1.z, a60);  a61 = fmaf(wb, e1.z, a61);
            a70 = fmaf(wa, e1.w, a70);  a71 = fmaf(wb, e1.w, a71);
        }
    }

    const float bb0 = bih[hp] + bhh[hp];
    const float bb1 = bih[hp + 64] + bhh[hp + 64];
    float* dst = P + (size_t)(v0 + rg8) * HID;
    dst[0*HID + hp] = a00 + bb0;  dst[0*HID + hp + 64] = a01 + bb1;
    dst[1*HID + hp] = a10 + bb0;  dst[1*HID + hp + 64] = a11 + bb1;
    dst[2*HID + hp] = a20 + bb0;  dst[2*HID + hp + 64] = a21 + bb1;
    dst[3*HID + hp] = a30 + bb0;  dst[3*HID + hp + 64] = a31 + bb1;
    dst[4*HID + hp] = a40 + bb0;  dst[4*HID + hp + 64] = a41 + bb1;
    dst[5*HID + hp] = a50 + bb0;  dst[5*HID + hp + 64] = a51 + bb1;
    dst[6*HID + hp] = a60 + bb0;  dst[6*HID + hp + 64] = a61 + bb1;
    dst[7*HID + hp] = a70 + bb0;  dst[7*HID + hp + 64] = a71 + bb1;
}

// ---------------------------------------------------------------------------
// Kernel A (fallback, R3-proven): used only if ws_size can't fit Wt + P.
// ---------------------------------------------------------------------------
__global__ __launch_bounds__(128)
void proj_fallback(const float* __restrict__ emb,
                   const float* __restrict__ Wih,
                   const float* __restrict__ bih,
                   const float* __restrict__ bhh,
                   float* __restrict__ P)
{
    __shared__ float et[DIM][ETP];
    const int t  = threadIdx.x;
    const int hp = t & 63;
    const int rg8 = (t >> 6) * 8;
    const int v0 = blockIdx.x * VT;

    #pragma unroll
    for (int r = 0; r < VT; ++r) {
        const float* src = emb + (size_t)(v0 + r) * DIM;
        for (int k = t; k < DIM; k += 128)
            et[k][r] = src[k];
    }
    __syncthreads();

    float a00=0.f,a10=0.f,a20=0.f,a30=0.f,a40=0.f,a50=0.f,a60=0.f,a70=0.f;
    float a01=0.f,a11=0.f,a21=0.f,a31=0.f,a41=0.f,a51=0.f,a61=0.f,a71=0.f;

    const float* w0 = Wih + (size_t)hp * DIM;
    const float* w1 = Wih + (size_t)(hp + 64) * DIM;

    for (int k4 = 0; k4 < DIM / 4; ++k4) {
        const float4 wa4 = *(const float4*)(w0 + k4 * 4);
        const float4 wb4 = *(const float4*)(w1 + k4 * 4);
        #pragma unroll
        for (int jj = 0; jj < 4; ++jj) {
            const float wa = (jj==0)?wa4.x:(jj==1)?wa4.y:(jj==2)?wa4.z:wa4.w;
            const float wb = (jj==0)?wb4.x:(jj==1)?wb4.y:(jj==2)?wb4.z:wb4.w;
            const int k = k4 * 4 + jj;
            const float4 e0 = *(const float4*)(&et[k][rg8]);
            const float4 e1 = *(const float4*)(&et[k][rg8 + 4]);
            a00 = fmaf(wa, e0.x, a00);  a01 = fmaf(wb, e0.x, a01);
            a10 = fmaf(wa, e0.y, a10);  a11 = fmaf(wb, e0.y, a11);
            a20 = fmaf(wa, e0.z, a20);  a21 = fmaf(wb, e0.z, a21);
            a30 = fmaf(wa, e0.w, a30);  a31 = fmaf(wb, e0.w, a31);
            a40 = fmaf(wa, e1.x, a40);  a41 = fmaf(wb, e1.x, a41);
            a50 = fmaf(wa, e1.y, a50);  a51 = fmaf(wb, e1.y, a51);
            a60 = fmaf(wa, e1.z, a60);  a61 = fmaf(wb, e1.z, a61);
            a70 = fmaf(wa, e1.w, a70);  a71 = fmaf(wb, e1.w, a71);
        }
    }

    const float bb0 = bih[hp] + bhh[hp];
    const float bb1 = bih[hp + 64] + bhh[hp + 64];
    float* dst = P + (size_t)(v0 + rg8) * HID;
    dst[0*HID + hp] = a00 + bb0;  dst[0*HID + hp + 64] = a01 + bb1;
    dst[1*HID + hp] = a10 + bb0;  dst[1*HID + hp + 64] = a11 + bb1;
    dst[2*HID + hp] = a20 + bb0;  dst[2*HID + hp + 64] = a21 + bb1;
    dst[3*HID + hp] = a30 + bb0;  dst[3*HID + hp + 64] = a31 + bb1;
    dst[4*HID + hp] = a40 + bb0;  dst[4*HID + hp + 64] = a41 + bb1;
    dst[5*HID + hp] = a50 + bb0;  dst[5*HID + hp + 64] = a51 + bb1;
    dst[6*HID + hp] = a60 + bb0;  dst[6*HID + hp + 64] = a61 + bb1;
    dst[7*HID + hp] = a70 + bb0;  dst[7*HID + hp + 64] = a71 + bb1;
}

// ---------------------------------------------------------------------------
// Kernel B: RNN (R7 structure: 512 thr, i=t>>2, kq=t&3, DPP quad reduce,
// chunked double-buffered x-proj LDS staging). R8 trims: 8 accumulators
// (FMA chain 32->16 cyc), unconditional quad-redundant h write (same value
// + same address from all 4 lanes -> no exec-mask ops).
// ---------------------------------------------------------------------------
__device__ __forceinline__ float quad_sum(float v)
{
    // xor1: quad_perm [1,0,3,2]=0xB1 ; xor2: quad_perm [2,3,0,1]=0x4E
    int x1 = __builtin_amdgcn_update_dpp(0, __float_as_int(v), 0xB1, 0xF, 0xF, true);
    v += __int_as_float(x1);
    int x2 = __builtin_amdgcn_update_dpp(0, __float_as_int(v), 0x4E, 0xF, 0xF, true);
    v += __int_as_float(x2);
    return v;   // all 4 lanes of the quad hold the sum
}

__global__ __launch_bounds__(512)
void rnn_kernel(const int* __restrict__ x,
                const float* __restrict__ Whh,
                const float* __restrict__ P,
                const float* __restrict__ fcw,
                const float* __restrict__ fcb,
                float* __restrict__ out)
{
    __shared__ float h0b[HID];
    __shared__ float h1b[HID];
    __shared__ int   toff[SEQ];          // token*HID, premultiplied
    __shared__ float xb[2 * 64 * HID];   // 64 KB: double-buffered x-proj chunks
    __shared__ float red[HID];

    const int t  = threadIdx.x;
    const int b  = blockIdx.x;
    const int i  = t >> 2;
    const int kq = t & 3;

    toff[t] = x[b * SEQ + t] * HID;
    if (t < HID) h0b[t] = 0.f;

    // W_hh[i][kq*32 + rot(j)*4 .. +3]; rotation -> 4 distinct bank-quads.
    float4 w[8];
    #pragma unroll
    for (int j = 0; j < 8; ++j) {
        const int pj = (j + 2 * kq) & 7;
        w[j] = *(const float4*)(Whh + (size_t)i * HID + kq * 32 + pj * 4);
    }
    __syncthreads();   // toff visible

#define STAGE(cn) do {                                                        \
        const int w_ = t >> 6, l_ = t & 63;                                   \
        const int base_ = ((cn) & 1) * (64 * HID);                            \
        _Pragma("unroll")                                                     \
        for (int q_ = 0; q_ < 4; ++q_) {                                      \
            const int row_ = w_ * 8 + q_ * 2 + (l_ >> 5);                     \
            const int col_ = (l_ & 31) * 4;                                   \
            const int off_ = toff[(cn) * 64 + row_] + col_;                   \
            const float4 v_ = *(const float4*)(P + off_);                     \
            *(float4*)(&xb[base_ + row_ * HID + col_]) = v_;                  \
        }                                                                     \
    } while (0)

    STAGE(0);
    __syncthreads();   // chunk 0 visible

    float hmax = -3.0e38f, hsum = 0.f;

#define STEP(HRD, HWR, XPTR, SOFF) do {                                       \
        const float xt = (XPTR)[(SOFF) * HID];                                \
        float ac0=0.f,ac1=0.f,ac2=0.f,ac3=0.f,ac4=0.f,ac5=0.f,ac6=0.f,ac7=0.f;\
        _Pragma("unroll")                                                     \
        for (int j = 0; j < 8; ++j) {                                         \
            const int pj = (j + 2 * kq) & 7;                                  \
            const float4 h4 = *(const float4*)((HRD) + kq * 32 + pj * 4);     \
            float* ap = (j==0)?&ac0:(j==1)?&ac1:(j==2)?&ac2:(j==3)?&ac3       \
                       :(j==4)?&ac4:(j==5)?&ac5:(j==6)?&ac6:&ac7;             \
            *ap = fmaf(w[j].x, h4.x, *ap);                                    \
            *ap = fmaf(w[j].y, h4.y, *ap);                                    \
            *ap = fmaf(w[j].z, h4.z, *ap);                                    \
            *ap = fmaf(w[j].w, h4.w, *ap);                                    \
        }                                                                     \
        float acc = ((ac0+ac1)+(ac2+ac3)) + ((ac4+ac5)+(ac6+ac7));            \
        acc = quad_sum(acc);                                                  \
        const float z = xt + acc;                                             \
        const float e = __builtin_amdgcn_exp2f(z * 2.8853900817779268f);      \
        const float hnew = fmaf(-2.f, __builtin_amdgcn_rcpf(e + 1.f), 1.f);   \
        hmax = fmaxf(hmax, hnew);                                             \
        hsum += hnew;                                                         \
        (HWR)[i] = hnew;   /* all 4 quad lanes: same value, same address */   \
        __syncthreads();                                                      \
    } while (0)

    for (int c = 0; c < 8; ++c) {
        if (c < 7) STAGE(c + 1);                 // double-buffered prefetch
        const float* xp = &xb[(c & 1) * (64 * HID) + i];
        #pragma unroll 4
        for (int u = 0; u < 32; ++u) {
            STEP(h0b, h1b, xp, u * 2);
            STEP(h1b, h0b, xp, u * 2 + 1);
        }
    }
#undef STEP
#undef STAGE

    // fused pooling + FC: out[b] = fcw[0:128]·hmax + fcw[128:256]·mean + fcb
    if (kq == 0)
        red[i] = fcw[i] * hmax + fcw[HID + i] * (hsum * (1.f / 512.f));
    __syncthreads();
    if (t < 64) {
        float v = red[t] + red[t + 64];
        #pragma unroll
        for (int m = 32; m >= 1; m >>= 1) v += __shfl_xor(v, m);
        if (t == 0) out[b] = v + fcb[0];
    }
}

// ---------------------------------------------------------------------------
extern "C" void kernel_launch(void* const* d_in, const int* in_sizes, int n_in,
                              void* d_out, int out_size, void* d_ws, size_t ws_size,
                              hipStream_t stream)
{
    const int*   x   = (const int*)  d_in[0];
    const float* emb = (const float*)d_in[1];
    const float* Wih = (const float*)d_in[2];
    const float* Whh = (const float*)d_in[3];
    const float* bih = (const float*)d_in[4];
    const float* bhh = (const float*)d_in[5];
    const float* fcw = (const float*)d_in[6];
    const float* fcb = (const float*)d_in[7];

    float* base = (float*)d_ws;
    const size_t need = (WT_FLOATS + (size_t)VOCAB * HID) * sizeof(float);
    float* P;

    if (ws_size >= need) {
        float* Wt = base;                 // 160 KB, inside d_ws (proven R4)
        P = base + WT_FLOATS;
        wtrans_kernel<<<(HID * DIM + 255) / 256, 256, 0, stream>>>(Wih, Wt);
        proj_fast<<<VOCAB / VT, 128, 0, stream>>>(emb, Wt, bih, bhh, P);
    } else {
        P = base;
        proj_fallback<<<VOCAB / VT, 128, 0, stream>>>(emb, Wih, bih, bhh, P);
    }

    rnn_kernel<<<BATCH, 512, 0, stream>>>(x, Whh, P, fcw, fcb, (float*)d_out);
}